// Round 1
// baseline (2819.562 us; speedup 1.0000x reference)
//
#include <hip/hip_runtime.h>
#include <math.h>

#define NB 16
#define NH 64
#define NPTS 2048
#define NEIGHS 20
#define KSEL 512
#define EPSV 1e-5f

// output layout (floats), reference return order
#define OFF_SEQ 0
#define OFF_VAL (NB*NH*KSEL)            // 524288
#define OFF_IDX (OFF_VAL + NB*KSEL)     // 532480
#define OFF_RET (OFF_IDX + NB*KSEL)     // 540672
#define OFF_XST (OFF_RET + NB*2*NPTS)   // 606208
#define OFF_XO  (OFF_XST + NB*3*KSEL)   // 630784

__device__ __forceinline__ bool better(float av, int ai, float bv, int bi) {
  return (av > bv) || (av == bv && ai < bi);
}

// replace-worst insert with fully static register indexing (no scratch)
__device__ __forceinline__ void topk_insert(float (&tv)[NEIGHS], int (&ti)[NEIGHS],
                                            float &wv, int &wi, float cv, int ci) {
  bool done = false;
  #pragma unroll
  for (int k = 0; k < NEIGHS; ++k) {
    bool hit = (!done) && (tv[k] == wv) && (ti[k] == wi);
    if (hit) { tv[k] = cv; ti[k] = ci; done = true; }
  }
  wv = tv[0]; wi = ti[0];
  #pragma unroll
  for (int k = 1; k < NEIGHS; ++k) {
    bool w = (tv[k] < wv) || (tv[k] == wv && ti[k] > wi);
    if (w) { wv = tv[k]; wi = ti[k]; }
  }
}

// K1: pts = relu(bn1(Wfc@seq1 + bfc)) in [b][n][o] layout, plus x2, G1, G2.
// One wave per 64 points: lane = point, per-point channel vector in registers.
__global__ __launch_bounds__(64) void k_fc(const float* __restrict__ seq1,
                                           const float* __restrict__ Wfc,
                                           const float* __restrict__ bfc,
                                           const float* __restrict__ b1g,
                                           const float* __restrict__ b1b,
                                           const float* __restrict__ b1m,
                                           const float* __restrict__ b1v,
                                           const float* __restrict__ Wec,
                                           float* __restrict__ pts,
                                           float* __restrict__ G1,
                                           float* __restrict__ G2,
                                           float* __restrict__ x2) {
  const int b = blockIdx.y, n0 = blockIdx.x * 64, l = threadIdx.x;
  const int n = n0 + l;
  __shared__ float ptL[64*65];
  const float* sq = seq1 + (size_t)b*NH*NPTS + n;
  float x[64];
  #pragma unroll
  for (int c = 0; c < 64; ++c) x[c] = sq[(size_t)c*NPTS];
  const size_t rowOff = ((size_t)b*NPTS + n)*NH;
  for (int o = 0; o < 64; ++o) {
    float acc = 0.f;
    const float* ar = Wfc + o*64;  // lane-uniform -> scalar loads
    #pragma unroll
    for (int c = 0; c < 64; c += 4) {
      float4 a4 = *(const float4*)(ar + c);
      acc = fmaf(a4.x, x[c],   acc);
      acc = fmaf(a4.y, x[c+1], acc);
      acc = fmaf(a4.z, x[c+2], acc);
      acc = fmaf(a4.w, x[c+3], acc);
    }
    float s1 = b1g[o] / sqrtf(b1v[o] + EPSV);
    float y  = (acc + bfc[o] - b1m[o]) * s1 + b1b[o];
    y = fmaxf(y, 0.f);
    ptL[l*65 + o] = y;
    pts[rowOff + o] = y;
  }
  float pt[64];
  #pragma unroll
  for (int c = 0; c < 64; ++c) pt[c] = ptL[l*65 + c];
  float s2 = 0.f;
  #pragma unroll
  for (int c = 0; c < 64; ++c) s2 = fmaf(pt[c], pt[c], s2);
  x2[(size_t)b*NPTS + n] = s2;
  for (int o = 0; o < 64; ++o) {
    const float* w1 = Wec + o*128;
    float a1 = 0.f, a2 = 0.f;
    #pragma unroll
    for (int c = 0; c < 64; c += 4) {
      float4 u = *(const float4*)(w1 + c);
      float4 v = *(const float4*)(w1 + 64 + c);
      a1 = fmaf(u.x, pt[c],   a1); a1 = fmaf(u.y, pt[c+1], a1);
      a1 = fmaf(u.z, pt[c+2], a1); a1 = fmaf(u.w, pt[c+3], a1);
      a2 = fmaf(v.x, pt[c],   a2); a2 = fmaf(v.y, pt[c+1], a2);
      a2 = fmaf(v.z, pt[c+2], a2); a2 = fmaf(v.w, pt[c+3], a2);
    }
    G1[rowOff + o] = a1;
    G2[rowOff + o] = a2;
  }
}

// K2: fused pairwise-key GEMM + per-row top-20 (set only; order irrelevant downstream)
#define ROWS 32
#define COLT 128
#define RST 68
#define CST 68
#define DST 132

__global__ __launch_bounds__(256) void k_knn(const float* __restrict__ pts,
                                             const float* __restrict__ x2,
                                             int* __restrict__ nidx) {
  const int b = blockIdx.y;
  const int row0 = blockIdx.x * ROWS;
  const int tid = threadIdx.x;
  const int cg = tid & 31, rg = tid >> 5;   // phase A: 4 rows x 4 cols per thread
  const int prow = tid >> 3, pg = tid & 7;  // phase B: 8 threads per row

  __shared__ __align__(16) float rowS[ROWS*RST];
  __shared__ __align__(16) float colS[10240];   // also aliased as merge buffers
  __shared__ __align__(16) float dS[ROWS*DST];
  __shared__ float x2S[COLT];

  const float* ptsb = pts + (size_t)b*NPTS*NH;

  { // stage the 32 row vectors once
    int r = tid >> 3, g8 = (tid & 7) * 8;
    const float* src = ptsb + (size_t)(row0 + r)*NH + g8;
    *(float4*)&rowS[r*RST + g8]     = *(const float4*)(src);
    *(float4*)&rowS[r*RST + g8 + 4] = *(const float4*)(src + 4);
  }

  float tv[NEIGHS]; int ti[NEIGHS];
  #pragma unroll
  for (int k = 0; k < NEIGHS; ++k) { tv[k] = -3.0e38f; ti[k] = 0x7fffffff; }
  float wv = -3.0e38f; int wi = 0x7fffffff;

  for (int ct = 0; ct < NPTS; ct += COLT) {
    __syncthreads();
    { // stage 128 column vectors + their x2
      int r = tid >> 1, h = (tid & 1) * 32;
      const float* src = ptsb + (size_t)(ct + r)*NH + h;
      #pragma unroll
      for (int q = 0; q < 8; ++q)
        *(float4*)&colS[r*CST + h + q*4] = *(const float4*)(src + q*4);
      if (tid < COLT) x2S[tid] = x2[(size_t)b*NPTS + ct + tid];
    }
    __syncthreads();
    float acc[4][4];
    #pragma unroll
    for (int i = 0; i < 4; ++i)
      #pragma unroll
      for (int j = 0; j < 4; ++j) acc[i][j] = 0.f;
    #pragma unroll
    for (int c = 0; c < NH; c += 4) {
      float4 rv[4], cv4[4];
      #pragma unroll
      for (int i = 0; i < 4; ++i) rv[i]  = *(const float4*)&rowS[(rg*4+i)*RST + c];
      #pragma unroll
      for (int j = 0; j < 4; ++j) cv4[j] = *(const float4*)&colS[(cg+32*j)*CST + c];
      #pragma unroll
      for (int i = 0; i < 4; ++i)
        #pragma unroll
        for (int j = 0; j < 4; ++j) {
          acc[i][j] = fmaf(rv[i].x, cv4[j].x, acc[i][j]);
          acc[i][j] = fmaf(rv[i].y, cv4[j].y, acc[i][j]);
          acc[i][j] = fmaf(rv[i].z, cv4[j].z, acc[i][j]);
          acc[i][j] = fmaf(rv[i].w, cv4[j].w, acc[i][j]);
        }
    }
    #pragma unroll
    for (int i = 0; i < 4; ++i)
      #pragma unroll
      for (int j = 0; j < 4; ++j) {
        int m = cg + 32*j;
        dS[(rg*4+i)*DST + m] = fmaf(2.0f, acc[i][j], -x2S[m]); // 2*dot - x2[m]
      }
    __syncthreads();
    for (int jj = 0; jj < 16; ++jj) {
      int m = pg + 8*jj;
      float cv = dS[prow*DST + m];
      int ci = ct + m;
      if (better(cv, ci, wv, wi)) topk_insert(tv, ti, wv, wi, cv, ci);
    }
  }

  __syncthreads();
  float* mergeV = colS;
  int*   mergeI = (int*)colS + 5120;
  #pragma unroll
  for (int k = 0; k < NEIGHS; ++k) {
    mergeV[tid*NEIGHS + k] = tv[k];
    mergeI[tid*NEIGHS + k] = ti[k];
  }
  __syncthreads();
  if (tid < ROWS) {
    float fv[NEIGHS]; int fi[NEIGHS];
    #pragma unroll
    for (int k = 0; k < NEIGHS; ++k) { fv[k] = -3.0e38f; fi[k] = 0x7fffffff; }
    float mwv = -3.0e38f; int mwi = 0x7fffffff;
    for (int s = 0; s < 8*NEIGHS; ++s) {
      float cv = mergeV[tid*(8*NEIGHS) + s];
      int   ci = mergeI[tid*(8*NEIGHS) + s];
      if (better(cv, ci, mwv, mwi)) topk_insert(fv, fi, mwv, mwi, cv, ci);
    }
    int* dst = nidx + ((size_t)b*NPTS + row0 + tid)*NEIGHS;
    #pragma unroll
    for (int k = 0; k < NEIGHS; ++k) dst[k] = fi[k];
  }
}

// K3: per-point neighbor max -> X -> v = Wb@X -> sc1/sc2/ret. One wave per point.
__global__ __launch_bounds__(256) void k_score(const float* __restrict__ pts,
    const float* __restrict__ G1, const float* __restrict__ G2,
    const int* __restrict__ nidx, const int* __restrict__ perm,
    const float* __restrict__ Wb,
    const float* __restrict__ b2g, const float* __restrict__ b2b,
    const float* __restrict__ b2m, const float* __restrict__ b2v,
    const float* __restrict__ bb,
    float* __restrict__ sc1w, float* __restrict__ out) {
  const int b = blockIdx.y;
  const int n0 = blockIdx.x * 16;
  const int tid = threadIdx.x, l = tid & 63, w = tid >> 6;
  __shared__ float WbS[64*65];
  for (int i = tid; i < 64*64; i += 256) WbS[(i >> 6)*65 + (i & 63)] = Wb[i];
  __syncthreads();
  const float sc2v = b2g[l] / sqrtf(b2v[l] + EPSV);
  const float mean2 = b2m[l], beta2 = b2b[l];
  const float bbv = bb[0];
  const float* G1b = G1 + (size_t)b*NPTS*NH;
  for (int it = 0; it < 4; ++it) {
    const int n = n0 + it*4 + w;
    const size_t ro = (size_t)b*NPTS*NH + (size_t)n*NH;
    const float base = G2[ro + l] - G1[ro + l];
    const int* nb = nidx + ((size_t)b*NPTS + n)*NEIGHS;
    float mx = -3.0e38f;
    #pragma unroll
    for (int k = 0; k < NEIGHS; ++k) {
      int m = nb[k];
      float val = G1b[(size_t)m*NH + l] + base;
      float y = (val - mean2) * sc2v + beta2;
      y = (y >= 0.f) ? y : 0.2f*y;
      mx = fmaxf(mx, y);
    }
    float X = 1.f / (1.f + expf(-mx));
    double v = 0.0;
    #pragma unroll
    for (int d = 0; d < 64; ++d) {
      float xd = __shfl(X, d, 64);
      v += (double)WbS[l*65 + d] * (double)xd;
    }
    float p1 = pts[ro + l];
    int pn = perm[n];
    float p2 = pts[(size_t)b*NPTS*NH + (size_t)pn*NH + l];
    double s1 = (double)p1 * v;
    double s2 = (double)p2 * v;
    #pragma unroll
    for (int off = 32; off > 0; off >>= 1) {
      s1 += __shfl_xor(s1, off, 64);
      s2 += __shfl_xor(s2, off, 64);
    }
    if (l == 0) {
      float r1 = (float)(s1 + (double)bbv);
      float r2 = (float)(s2 + (double)bbv);
      sc1w[(size_t)b*NPTS + n] = r1;
      out[OFF_RET + (size_t)b*2*NPTS + n] = r1;
      out[OFF_RET + (size_t)b*2*NPTS + NPTS + n] = r2;
    }
  }
}

// K4: per-batch exact top-512 (value desc, idx asc) via u64 bitonic sort + gathers
__global__ __launch_bounds__(256) void k_select(const float* __restrict__ sc1w,
    const float* __restrict__ seq1, const float* __restrict__ xyz,
    float* __restrict__ out) {
  const int b = blockIdx.x, tid = threadIdx.x;
  __shared__ unsigned long long keys[NPTS];
  __shared__ float valS[KSEL];
  __shared__ int idxS[KSEL];
  for (int i = tid; i < NPTS; i += 256) {
    float f = sc1w[(size_t)b*NPTS + i];
    unsigned u = __float_as_uint(f);
    u = (u & 0x80000000u) ? ~u : (u | 0x80000000u);   // ascending-order map
    keys[i] = ((unsigned long long)(~u) << 32) | (unsigned)i; // sort asc = value desc, idx asc
  }
  __syncthreads();
  for (int k = 2; k <= NPTS; k <<= 1) {
    for (int j = k >> 1; j > 0; j >>= 1) {
      for (int i = tid; i < NPTS; i += 256) {
        int l2 = i ^ j;
        if (l2 > i) {
          unsigned long long a = keys[i], c = keys[l2];
          bool up = ((i & k) == 0);
          if ((a > c) == up) { keys[i] = c; keys[l2] = a; }
        }
      }
      __syncthreads();
    }
  }
  for (int i = tid; i < KSEL; i += 256) {
    unsigned long long key = keys[i];
    int sidx = (int)(key & 0xffffffffULL);
    unsigned u = ~(unsigned)(key >> 32);
    unsigned fb = (u & 0x80000000u) ? (u & 0x7fffffffu) : ~u;
    float f = __uint_as_float(fb);
    float val = 1.f / (1.f + expf(-f));
    valS[i] = val; idxS[i] = sidx;
    out[OFF_VAL + (size_t)b*KSEL + i] = val;
    out[OFF_IDX + (size_t)b*KSEL + i] = (float)sidx;
  }
  __syncthreads();
  for (int t = tid; t < NH*KSEL; t += 256) {
    int c = t >> 9, i = t & (KSEL-1);
    float sv = seq1[((size_t)b*NH + c)*NPTS + idxS[i]];
    out[OFF_SEQ + (((size_t)b*NH + c) << 9) + i] = sv * valS[i];
  }
  for (int t = tid; t < 3*KSEL; t += 256) {
    int c = t >> 9, i = t & (KSEL-1);
    float xv = xyz[((size_t)b*3 + c)*NPTS + idxS[i]];
    out[OFF_XST + (((size_t)b*3 + c) << 9) + i] = xv;
    out[OFF_XO  + (((size_t)b*3 + c) << 9) + i] = xv * valS[i];
  }
}

extern "C" void kernel_launch(void* const* d_in, const int* in_sizes, int n_in,
                              void* d_out, int out_size, void* d_ws, size_t ws_size,
                              hipStream_t stream) {
  const float* xyz  = (const float*)d_in[0];
  const float* seq1 = (const float*)d_in[1];
  const int*   perm = (const int*)d_in[2];
  const float* Wfc  = (const float*)d_in[3];
  const float* bfc  = (const float*)d_in[4];
  const float* b1g  = (const float*)d_in[5];
  const float* b1b  = (const float*)d_in[6];
  const float* b1m  = (const float*)d_in[7];
  const float* b1v  = (const float*)d_in[8];
  const float* Wec  = (const float*)d_in[9];
  const float* b2g  = (const float*)d_in[10];
  const float* b2b  = (const float*)d_in[11];
  const float* b2m  = (const float*)d_in[12];
  const float* b2v  = (const float*)d_in[13];
  const float* Wb   = (const float*)d_in[14];
  const float* bb   = (const float*)d_in[15];
  float* out = (float*)d_out;

  float* ws   = (float*)d_ws;
  float* pts  = ws;
  float* G1   = pts + (size_t)NB*NPTS*NH;
  float* G2   = G1  + (size_t)NB*NPTS*NH;
  float* x2   = G2  + (size_t)NB*NPTS*NH;
  float* sc1w = x2  + (size_t)NB*NPTS;
  int*   nidx = (int*)(sc1w + (size_t)NB*NPTS);

  hipLaunchKernelGGL(k_fc, dim3(NPTS/64, NB), dim3(64), 0, stream,
                     seq1, Wfc, bfc, b1g, b1b, b1m, b1v, Wec, pts, G1, G2, x2);
  hipLaunchKernelGGL(k_knn, dim3(NPTS/ROWS, NB), dim3(256), 0, stream,
                     pts, x2, nidx);
  hipLaunchKernelGGL(k_score, dim3(NPTS/16, NB), dim3(256), 0, stream,
                     pts, G1, G2, nidx, perm, Wb, b2g, b2b, b2m, b2v, bb, sc1w, out);
  hipLaunchKernelGGL(k_select, dim3(NB), dim3(256), 0, stream,
                     sc1w, seq1, xyz, out);
}

// Round 2
// 793.531 us; speedup vs baseline: 3.5532x; 3.5532x over previous
//
#include <hip/hip_runtime.h>
#include <math.h>

#define NB 16
#define NH 64
#define NPTS 2048
#define NEIGHS 20
#define KSEL 512
#define EPSV 1e-5f

// output layout (floats), reference return order
#define OFF_SEQ 0
#define OFF_VAL (NB*NH*KSEL)            // 524288
#define OFF_IDX (OFF_VAL + NB*KSEL)     // 532480
#define OFF_RET (OFF_IDX + NB*KSEL)     // 540672
#define OFF_XST (OFF_RET + NB*2*NPTS)   // 606208
#define OFF_XO  (OFF_XST + NB*3*KSEL)   // 630784

// K1: pts = relu(bn1(Wfc@seq1 + bfc)) in [b][n][o] layout, plus x2, G1, G2.
__global__ __launch_bounds__(64) void k_fc(const float* __restrict__ seq1,
                                           const float* __restrict__ Wfc,
                                           const float* __restrict__ bfc,
                                           const float* __restrict__ b1g,
                                           const float* __restrict__ b1b,
                                           const float* __restrict__ b1m,
                                           const float* __restrict__ b1v,
                                           const float* __restrict__ Wec,
                                           float* __restrict__ pts,
                                           float* __restrict__ G1,
                                           float* __restrict__ G2,
                                           float* __restrict__ x2) {
  const int b = blockIdx.y, n0 = blockIdx.x * 64, l = threadIdx.x;
  const int n = n0 + l;
  __shared__ float ptL[64*65];
  const float* sq = seq1 + (size_t)b*NH*NPTS + n;
  float x[64];
  #pragma unroll
  for (int c = 0; c < 64; ++c) x[c] = sq[(size_t)c*NPTS];
  const size_t rowOff = ((size_t)b*NPTS + n)*NH;
  for (int o = 0; o < 64; ++o) {
    float acc = 0.f;
    const float* ar = Wfc + o*64;  // lane-uniform -> scalar loads
    #pragma unroll
    for (int c = 0; c < 64; c += 4) {
      float4 a4 = *(const float4*)(ar + c);
      acc = fmaf(a4.x, x[c],   acc);
      acc = fmaf(a4.y, x[c+1], acc);
      acc = fmaf(a4.z, x[c+2], acc);
      acc = fmaf(a4.w, x[c+3], acc);
    }
    float s1 = b1g[o] / sqrtf(b1v[o] + EPSV);
    float y  = (acc + bfc[o] - b1m[o]) * s1 + b1b[o];
    y = fmaxf(y, 0.f);
    ptL[l*65 + o] = y;
    pts[rowOff + o] = y;
  }
  float pt[64];
  #pragma unroll
  for (int c = 0; c < 64; ++c) pt[c] = ptL[l*65 + c];
  float s2 = 0.f;
  #pragma unroll
  for (int c = 0; c < 64; ++c) s2 = fmaf(pt[c], pt[c], s2);
  x2[(size_t)b*NPTS + n] = s2;
  for (int o = 0; o < 64; ++o) {
    const float* w1 = Wec + o*128;
    float a1 = 0.f, a2 = 0.f;
    #pragma unroll
    for (int c = 0; c < 64; c += 4) {
      float4 u = *(const float4*)(w1 + c);
      float4 v = *(const float4*)(w1 + 64 + c);
      a1 = fmaf(u.x, pt[c],   a1); a1 = fmaf(u.y, pt[c+1], a1);
      a1 = fmaf(u.z, pt[c+2], a1); a1 = fmaf(u.w, pt[c+3], a1);
      a2 = fmaf(v.x, pt[c],   a2); a2 = fmaf(v.y, pt[c+1], a2);
      a2 = fmaf(v.z, pt[c+2], a2); a2 = fmaf(v.w, pt[c+3], a2);
    }
    G1[rowOff + o] = a1;
    G2[rowOff + o] = a2;
  }
}

// K2: fused pairwise-score GEMM + per-row exact top-20.
// Block: 64 rows, col tiles of 64. 256 threads.
// GEMM: 4x4 thread blocking; rowS/colS stride 68 (aligned b128, 2-way banks),
// dS stride 67 (conflict-free lane=row selection reads).
// Selection: lane l = row, wave w scans cols w*16..w*16+15 per tile.
// Monotone col idx within each wave's stream => strict '>' insertion gives
// exact jax (value desc, idx asc) tie-break with no idx compares.
#define DST 67
#define CSTR 68

__global__ __launch_bounds__(256) void k_knn(const float* __restrict__ pts,
                                             const float* __restrict__ x2,
                                             int* __restrict__ nidx) {
  const int b = blockIdx.y;
  const int row0 = blockIdx.x * 64;
  const int tid = threadIdx.x;
  const int rg = tid >> 4, cg = tid & 15;   // GEMM mapping
  const int l = tid & 63, w = tid >> 6;     // selection mapping

  __shared__ float smem[13056];             // 52.2 KB -> 3 blocks/CU
  float* rowS = smem;                       // [64][68]
  float* colS = smem + 4352;                // [64][68]
  float* dS   = smem + 8704;                // [64][67]
  float* x2S  = smem + 12992;               // [64]

  const float* ptsb = pts + (size_t)b*NPTS*NH;

  { // stage the 64 row vectors once (col-per-lane: conflict-free b128 writes)
    int rr = tid & 63, f0 = (tid >> 6) * 16;
    const float* src = ptsb + (size_t)(row0 + rr)*NH + f0;
    #pragma unroll
    for (int q = 0; q < 4; ++q)
      *(float4*)&rowS[rr*CSTR + f0 + 4*q] = *(const float4*)(src + 4*q);
  }

  float Lv[20]; int Li[20];
  #pragma unroll
  for (int k = 0; k < 20; ++k) { Lv[k] = -3.0e38f; Li[k] = 0x7fffffff; }

  for (int ct = 0; ct < NPTS; ct += 64) {
    __syncthreads();   // prev tile's dS consumed, colS consumed
    { // stage 64 col vectors + x2
      int cl = tid & 63, f0 = (tid >> 6) * 16;
      const float* src = ptsb + (size_t)(ct + cl)*NH + f0;
      #pragma unroll
      for (int q = 0; q < 4; ++q)
        *(float4*)&colS[cl*CSTR + f0 + 4*q] = *(const float4*)(src + 4*q);
      if (tid < 64) x2S[tid] = x2[(size_t)b*NPTS + ct + tid];
    }
    __syncthreads();
    { // GEMM: thread (rg,cg) -> rows rg*4+i, cols cg+16*j
      float acc[4][4];
      #pragma unroll
      for (int i = 0; i < 4; ++i)
        #pragma unroll
        for (int j = 0; j < 4; ++j) acc[i][j] = 0.f;
      #pragma unroll
      for (int c = 0; c < NH; c += 4) {
        float4 rv[4], cv[4];
        #pragma unroll
        for (int i = 0; i < 4; ++i) rv[i] = *(const float4*)&rowS[(rg*4+i)*CSTR + c];
        #pragma unroll
        for (int j = 0; j < 4; ++j) cv[j] = *(const float4*)&colS[(cg+16*j)*CSTR + c];
        #pragma unroll
        for (int i = 0; i < 4; ++i)
          #pragma unroll
          for (int j = 0; j < 4; ++j) {
            acc[i][j] = fmaf(rv[i].x, cv[j].x, acc[i][j]);
            acc[i][j] = fmaf(rv[i].y, cv[j].y, acc[i][j]);
            acc[i][j] = fmaf(rv[i].z, cv[j].z, acc[i][j]);
            acc[i][j] = fmaf(rv[i].w, cv[j].w, acc[i][j]);
          }
      }
      #pragma unroll
      for (int i = 0; i < 4; ++i)
        #pragma unroll
        for (int j = 0; j < 4; ++j) {
          int cc = cg + 16*j;
          // rank key: 2*dot - x2[col]  (row term is rank-invariant per row)
          dS[(rg*4+i)*DST + cc] = fmaf(2.0f, acc[i][j], -x2S[cc]);
        }
    }
    __syncthreads();
    { // selection: 16 candidates per lane, strict-> bubble-carry insert
      #pragma unroll
      for (int s = 0; s < 16; ++s) {
        float v = dS[l*DST + w*16 + s];
        int  ci = ct + w*16 + s;
        if (v > Lv[19]) {
          float cv = v; int cidx = ci;
          #pragma unroll
          for (int k = 0; k < 20; ++k) {
            bool c = cv > Lv[k];
            float nv = c ? cv : Lv[k];
            int   ni = c ? cidx : Li[k];
            float ov = Lv[k]; int oi = Li[k];
            cv   = c ? ov : cv;
            cidx = c ? oi : cidx;
            Lv[k] = nv; Li[k] = ni;
          }
        }
      }
    }
  }

  // merge the 4 per-wave partial lists per row (full (val, idx asc) comparator)
  __syncthreads();
  float* mV = smem;                 // [4][64][20] floats (overlays rowS/colS)
  int*   mI = (int*)smem + 5120;    // [4][64][20] ints (overlays colS/dS - ok, regs hold lists)
  #pragma unroll
  for (int k = 0; k < 20; ++k) {
    mV[(w*64 + l)*20 + k] = Lv[k];
    mI[(w*64 + l)*20 + k] = Li[k];
  }
  __syncthreads();
  if (w == 0) {  // wave 0's Lv/Li already = stream-0 exact list
    for (int ws = 1; ws < 4; ++ws) {
      #pragma unroll
      for (int k = 0; k < 20; ++k) {
        float cv = mV[(ws*64 + l)*20 + k];
        int   ci = mI[(ws*64 + l)*20 + k];
        bool ins = (cv > Lv[19]) || (cv == Lv[19] && ci < Li[19]);
        if (ins) {
          float c0 = cv; int i0 = ci;
          #pragma unroll
          for (int k2 = 0; k2 < 20; ++k2) {
            bool c = (c0 > Lv[k2]) || (c0 == Lv[k2] && i0 < Li[k2]);
            float nv = c ? c0 : Lv[k2];
            int   ni = c ? i0 : Li[k2];
            float ov = Lv[k2]; int oi = Li[k2];
            c0 = c ? ov : c0;
            i0 = c ? oi : i0;
            Lv[k2] = nv; Li[k2] = ni;
          }
        }
      }
    }
    int* dst = nidx + ((size_t)b*NPTS + row0 + l)*NEIGHS;
    #pragma unroll
    for (int k = 0; k < 20; ++k) dst[k] = Li[k];
  }
}

// K3: per-point neighbor max -> X -> v = Wb@X -> sc1/sc2/ret. One wave per point.
__global__ __launch_bounds__(256) void k_score(const float* __restrict__ pts,
    const float* __restrict__ G1, const float* __restrict__ G2,
    const int* __restrict__ nidx, const int* __restrict__ perm,
    const float* __restrict__ Wb,
    const float* __restrict__ b2g, const float* __restrict__ b2b,
    const float* __restrict__ b2m, const float* __restrict__ b2v,
    const float* __restrict__ bb,
    float* __restrict__ sc1w, float* __restrict__ out) {
  const int b = blockIdx.y;
  const int n0 = blockIdx.x * 16;
  const int tid = threadIdx.x, l = tid & 63, w = tid >> 6;
  __shared__ float WbS[64*65];
  for (int i = tid; i < 64*64; i += 256) WbS[(i >> 6)*65 + (i & 63)] = Wb[i];
  __syncthreads();
  const float sc2v = b2g[l] / sqrtf(b2v[l] + EPSV);
  const float mean2 = b2m[l], beta2 = b2b[l];
  const float bbv = bb[0];
  const float* G1b = G1 + (size_t)b*NPTS*NH;
  for (int it = 0; it < 4; ++it) {
    const int n = n0 + it*4 + w;
    const size_t ro = (size_t)b*NPTS*NH + (size_t)n*NH;
    const float base = G2[ro + l] - G1[ro + l];
    const int* nb = nidx + ((size_t)b*NPTS + n)*NEIGHS;
    float mx = -3.0e38f;
    #pragma unroll
    for (int k = 0; k < NEIGHS; ++k) {
      int m = nb[k];
      float val = G1b[(size_t)m*NH + l] + base;
      float y = (val - mean2) * sc2v + beta2;
      y = (y >= 0.f) ? y : 0.2f*y;
      mx = fmaxf(mx, y);
    }
    float X = 1.f / (1.f + expf(-mx));
    double v = 0.0;
    #pragma unroll
    for (int d = 0; d < 64; ++d) {
      float xd = __shfl(X, d, 64);
      v += (double)WbS[l*65 + d] * (double)xd;
    }
    float p1 = pts[ro + l];
    int pn = perm[n];
    float p2 = pts[(size_t)b*NPTS*NH + (size_t)pn*NH + l];
    double s1 = (double)p1 * v;
    double s2 = (double)p2 * v;
    #pragma unroll
    for (int off = 32; off > 0; off >>= 1) {
      s1 += __shfl_xor(s1, off, 64);
      s2 += __shfl_xor(s2, off, 64);
    }
    if (l == 0) {
      float r1 = (float)(s1 + (double)bbv);
      float r2 = (float)(s2 + (double)bbv);
      sc1w[(size_t)b*NPTS + n] = r1;
      out[OFF_RET + (size_t)b*2*NPTS + n] = r1;
      out[OFF_RET + (size_t)b*2*NPTS + NPTS + n] = r2;
    }
  }
}

// K4: per-batch exact top-512 (value desc, idx asc) via u64 bitonic sort + gathers
__global__ __launch_bounds__(256) void k_select(const float* __restrict__ sc1w,
    const float* __restrict__ seq1, const float* __restrict__ xyz,
    float* __restrict__ out) {
  const int b = blockIdx.x, tid = threadIdx.x;
  __shared__ unsigned long long keys[NPTS];
  __shared__ float valS[KSEL];
  __shared__ int idxS[KSEL];
  for (int i = tid; i < NPTS; i += 256) {
    float f = sc1w[(size_t)b*NPTS + i];
    unsigned u = __float_as_uint(f);
    u = (u & 0x80000000u) ? ~u : (u | 0x80000000u);   // ascending-order map
    keys[i] = ((unsigned long long)(~u) << 32) | (unsigned)i; // asc sort = value desc, idx asc
  }
  __syncthreads();
  for (int k = 2; k <= NPTS; k <<= 1) {
    for (int j = k >> 1; j > 0; j >>= 1) {
      for (int i = tid; i < NPTS; i += 256) {
        int l2 = i ^ j;
        if (l2 > i) {
          unsigned long long a = keys[i], c = keys[l2];
          bool up = ((i & k) == 0);
          if ((a > c) == up) { keys[i] = c; keys[l2] = a; }
        }
      }
      __syncthreads();
    }
  }
  for (int i = tid; i < KSEL; i += 256) {
    unsigned long long key = keys[i];
    int sidx = (int)(key & 0xffffffffULL);
    unsigned u = ~(unsigned)(key >> 32);
    unsigned fb = (u & 0x80000000u) ? (u & 0x7fffffffu) : ~u;
    float f = __uint_as_float(fb);
    float val = 1.f / (1.f + expf(-f));
    valS[i] = val; idxS[i] = sidx;
    out[OFF_VAL + (size_t)b*KSEL + i] = val;
    out[OFF_IDX + (size_t)b*KSEL + i] = (float)sidx;
  }
  __syncthreads();
  for (int t = tid; t < NH*KSEL; t += 256) {
    int c = t >> 9, i = t & (KSEL-1);
    float sv = seq1[((size_t)b*NH + c)*NPTS + idxS[i]];
    out[OFF_SEQ + (((size_t)b*NH + c) << 9) + i] = sv * valS[i];
  }
  for (int t = tid; t < 3*KSEL; t += 256) {
    int c = t >> 9, i = t & (KSEL-1);
    float xv = xyz[((size_t)b*3 + c)*NPTS + idxS[i]];
    out[OFF_XST + (((size_t)b*3 + c) << 9) + i] = xv;
    out[OFF_XO  + (((size_t)b*3 + c) << 9) + i] = xv * valS[i];
  }
}

extern "C" void kernel_launch(void* const* d_in, const int* in_sizes, int n_in,
                              void* d_out, int out_size, void* d_ws, size_t ws_size,
                              hipStream_t stream) {
  const float* xyz  = (const float*)d_in[0];
  const float* seq1 = (const float*)d_in[1];
  const int*   perm = (const int*)d_in[2];
  const float* Wfc  = (const float*)d_in[3];
  const float* bfc  = (const float*)d_in[4];
  const float* b1g  = (const float*)d_in[5];
  const float* b1b  = (const float*)d_in[6];
  const float* b1m  = (const float*)d_in[7];
  const float* b1v  = (const float*)d_in[8];
  const float* Wec  = (const float*)d_in[9];
  const float* b2g  = (const float*)d_in[10];
  const float* b2b  = (const float*)d_in[11];
  const float* b2m  = (const float*)d_in[12];
  const float* b2v  = (const float*)d_in[13];
  const float* Wb   = (const float*)d_in[14];
  const float* bb   = (const float*)d_in[15];
  float* out = (float*)d_out;

  float* ws   = (float*)d_ws;
  float* pts  = ws;
  float* G1   = pts + (size_t)NB*NPTS*NH;
  float* G2   = G1  + (size_t)NB*NPTS*NH;
  float* x2   = G2  + (size_t)NB*NPTS*NH;
  float* sc1w = x2  + (size_t)NB*NPTS;
  int*   nidx = (int*)(sc1w + (size_t)NB*NPTS);

  hipLaunchKernelGGL(k_fc, dim3(NPTS/64, NB), dim3(64), 0, stream,
                     seq1, Wfc, bfc, b1g, b1b, b1m, b1v, Wec, pts, G1, G2, x2);
  hipLaunchKernelGGL(k_knn, dim3(NPTS/64, NB), dim3(256), 0, stream,
                     pts, x2, nidx);
  hipLaunchKernelGGL(k_score, dim3(NPTS/16, NB), dim3(256), 0, stream,
                     pts, G1, G2, nidx, perm, Wb, b2g, b2b, b2m, b2v, bb, sc1w, out);
  hipLaunchKernelGGL(k_select, dim3(NB), dim3(256), 0, stream,
                     sc1w, seq1, xyz, out);
}

// Round 4
// 721.584 us; speedup vs baseline: 3.9075x; 1.0997x over previous
//
#include <hip/hip_runtime.h>
#include <math.h>

#define NB 16
#define NH 64
#define NPTS 2048
#define NEIGHS 20
#define KSEL 512
#define EPSV 1e-5f
#define NINF -3.0e38f

// output layout (floats), reference return order
#define OFF_SEQ 0
#define OFF_VAL (NB*NH*KSEL)            // 524288
#define OFF_IDX (OFF_VAL + NB*KSEL)     // 532480
#define OFF_RET (OFF_IDX + NB*KSEL)     // 540672
#define OFF_XST (OFF_RET + NB*2*NPTS)   // 606208
#define OFF_XO  (OFF_XST + NB*3*KSEL)   // 630784

__device__ __forceinline__ bool better(float av, int ai, float bv, int bi) {
  return (av > bv) || (av == bv && ai < bi);
}

// strict-> bubble insert into sorted-desc 20-list (value-only compare; callers
// guarantee idx-ascending candidate order within each stream)
__device__ __forceinline__ void ins20(float (&Lv)[20], int (&Li)[20], float cv, int ci) {
  #pragma unroll
  for (int k = 0; k < 20; ++k) {
    bool c = cv > Lv[k];
    float nv = c ? cv : Lv[k];
    int   ni = c ? ci : Li[k];
    float ov = Lv[k]; int oi = Li[k];
    cv = c ? ov : cv;
    ci = c ? oi : ci;
    Lv[k] = nv; Li[k] = ni;
  }
}

// K1: pts = relu(bn1(Wfc@seq1 + bfc)) in [b][n][o] layout, plus x2, G1, G2.
// Arithmetic is EXACTLY the R2 (passing) sequential fmaf chains — bitwise
// stable. Only change: outputs staged in LDS and stored coalesced
// (lane-consecutive), replacing 256B-stride scatter writes.
__global__ __launch_bounds__(64) void k_fc(const float* __restrict__ seq1,
                                           const float* __restrict__ Wfc,
                                           const float* __restrict__ bfc,
                                           const float* __restrict__ b1g,
                                           const float* __restrict__ b1b,
                                           const float* __restrict__ b1m,
                                           const float* __restrict__ b1v,
                                           const float* __restrict__ Wec,
                                           float* __restrict__ pts,
                                           float* __restrict__ G1,
                                           float* __restrict__ G2,
                                           float* __restrict__ x2) {
  const int b = blockIdx.y, n0 = blockIdx.x * 64, l = threadIdx.x;
  const int n = n0 + l;
  __shared__ float ptL[64*65];
  const float* sq = seq1 + (size_t)b*NH*NPTS + n;
  float x[64];
  #pragma unroll
  for (int c = 0; c < 64; ++c) x[c] = sq[(size_t)c*NPTS];

  // phase 1: fc + bn1 + relu  (exact R2 chain)
  for (int o = 0; o < 64; ++o) {
    float acc = 0.f;
    const float* ar = Wfc + o*64;    // lane-uniform -> scalar loads
    #pragma unroll
    for (int c = 0; c < 64; c += 4) {
      float4 a4 = *(const float4*)(ar + c);
      acc = fmaf(a4.x, x[c],   acc);
      acc = fmaf(a4.y, x[c+1], acc);
      acc = fmaf(a4.z, x[c+2], acc);
      acc = fmaf(a4.w, x[c+3], acc);
    }
    float s1 = b1g[o] / sqrtf(b1v[o] + EPSV);
    float y  = (acc + bfc[o] - b1m[o]) * s1 + b1b[o];
    ptL[l*65 + o] = fmaxf(y, 0.f);
  }
  float pt[64];
  #pragma unroll
  for (int c = 0; c < 64; ++c) pt[c] = ptL[l*65 + c];
  {
    float s2 = 0.f;
    #pragma unroll
    for (int c = 0; c < 64; ++c) s2 = fmaf(pt[c], pt[c], s2);
    x2[(size_t)b*NPTS + n] = s2;
  }
  const size_t base = ((size_t)b*NPTS + n0)*NH;
  __syncthreads();
  // coalesced flush: lane l writes channel l of point t
  #pragma unroll 4
  for (int t = 0; t < 64; ++t) pts[base + t*64 + l] = ptL[t*65 + l];
  __syncthreads();

  // phase 2a: G1 = pts . Wec[:, :64]^T  (exact R2 per-value chain)
  for (int o = 0; o < 64; ++o) {
    const float* w1 = Wec + o*128;
    float a1 = 0.f;
    #pragma unroll
    for (int c = 0; c < 64; c += 4) {
      float4 u = *(const float4*)(w1 + c);
      a1 = fmaf(u.x, pt[c],   a1); a1 = fmaf(u.y, pt[c+1], a1);
      a1 = fmaf(u.z, pt[c+2], a1); a1 = fmaf(u.w, pt[c+3], a1);
    }
    ptL[l*65 + o] = a1;
  }
  __syncthreads();
  #pragma unroll 4
  for (int t = 0; t < 64; ++t) G1[base + t*64 + l] = ptL[t*65 + l];
  __syncthreads();

  // phase 2b: G2 = pts . Wec[:, 64:]^T  (exact R2 per-value chain)
  for (int o = 0; o < 64; ++o) {
    const float* w2 = Wec + o*128 + 64;
    float a2 = 0.f;
    #pragma unroll
    for (int c = 0; c < 64; c += 4) {
      float4 v = *(const float4*)(w2 + c);
      a2 = fmaf(v.x, pt[c],   a2); a2 = fmaf(v.y, pt[c+1], a2);
      a2 = fmaf(v.z, pt[c+2], a2); a2 = fmaf(v.w, pt[c+3], a2);
    }
    ptL[l*65 + o] = a2;
  }
  __syncthreads();
  #pragma unroll 4
  for (int t = 0; t < 64; ++t) G2[base + t*64 + l] = ptL[t*65 + l];
}

// K2: fused pairwise-score GEMM + per-row exact top-20.
// Selection uses a 4-deep register shift-FIFO: sorted-insert only fires
// when __any(cnt>=4). Exact: stale threshold only over-accepts (monotone),
// ins20 filters; oldest-first flush preserves idx-ascending tie-break.
#define DST 67
#define CSTR 68

__global__ __launch_bounds__(256) void k_knn(const float* __restrict__ pts,
                                             const float* __restrict__ x2,
                                             int* __restrict__ nidx) {
  const int b = blockIdx.y;
  const int row0 = blockIdx.x * 64;
  const int tid = threadIdx.x;
  const int rg = tid >> 4, cg = tid & 15;   // GEMM mapping
  const int l = tid & 63, w = tid >> 6;     // selection mapping

  __shared__ float smem[13056];             // 52.2 KB
  float* rowS = smem;                       // [64][68]
  float* colS = smem + 4352;                // [64][68]
  float* dS   = smem + 8704;                // [64][67]
  float* x2S  = smem + 12992;               // [64]

  const float* ptsb = pts + (size_t)b*NPTS*NH;

  { // stage the 64 row vectors once
    int rr = tid & 63, f0 = (tid >> 6) * 16;
    const float* src = ptsb + (size_t)(row0 + rr)*NH + f0;
    #pragma unroll
    for (int q = 0; q < 4; ++q)
      *(float4*)&rowS[rr*CSTR + f0 + 4*q] = *(const float4*)(src + 4*q);
  }

  float Lv[20]; int Li[20];
  #pragma unroll
  for (int k = 0; k < 20; ++k) { Lv[k] = NINF; Li[k] = 0x7fffffff; }
  // 4-deep shift FIFO (f3 oldest)
  float f0v = NINF, f1v = NINF, f2v = NINF, f3v = NINF;
  int   f0i = 0,    f1i = 0,    f2i = 0,    f3i = 0;
  int   cnt = 0;

  for (int ct = 0; ct < NPTS; ct += 64) {
    __syncthreads();
    { // stage 64 col vectors + x2
      int cl = tid & 63, f0_ = (tid >> 6) * 16;
      const float* src = ptsb + (size_t)(ct + cl)*NH + f0_;
      #pragma unroll
      for (int q = 0; q < 4; ++q)
        *(float4*)&colS[cl*CSTR + f0_ + 4*q] = *(const float4*)(src + 4*q);
      if (tid < 64) x2S[tid] = x2[(size_t)b*NPTS + ct + tid];
    }
    __syncthreads();
    { // GEMM: thread (rg,cg) -> rows rg*4+i, cols cg+16*j
      float acc[4][4];
      #pragma unroll
      for (int i = 0; i < 4; ++i)
        #pragma unroll
        for (int j = 0; j < 4; ++j) acc[i][j] = 0.f;
      #pragma unroll
      for (int c = 0; c < NH; c += 4) {
        float4 rv[4], cv[4];
        #pragma unroll
        for (int i = 0; i < 4; ++i) rv[i] = *(const float4*)&rowS[(rg*4+i)*CSTR + c];
        #pragma unroll
        for (int j = 0; j < 4; ++j) cv[j] = *(const float4*)&colS[(cg+16*j)*CSTR + c];
        #pragma unroll
        for (int i = 0; i < 4; ++i)
          #pragma unroll
          for (int j = 0; j < 4; ++j) {
            acc[i][j] = fmaf(rv[i].x, cv[j].x, acc[i][j]);
            acc[i][j] = fmaf(rv[i].y, cv[j].y, acc[i][j]);
            acc[i][j] = fmaf(rv[i].z, cv[j].z, acc[i][j]);
            acc[i][j] = fmaf(rv[i].w, cv[j].w, acc[i][j]);
          }
      }
      #pragma unroll
      for (int i = 0; i < 4; ++i)
        #pragma unroll
        for (int j = 0; j < 4; ++j) {
          int cc = cg + 16*j;
          dS[(rg*4+i)*DST + cc] = fmaf(2.0f, acc[i][j], -x2S[cc]);
        }
    }
    __syncthreads();
    { // selection: 16 candidates/lane; FIFO append, deferred flush
      const float* dRow = dS + l*DST + w*16;
      #pragma unroll
      for (int s = 0; s < 16; ++s) {
        float v = dRow[s];
        int  ci = ct + w*16 + s;
        bool pass = v > Lv[19];
        f3v = pass ? f2v : f3v;  f3i = pass ? f2i : f3i;
        f2v = pass ? f1v : f2v;  f2i = pass ? f1i : f2i;
        f1v = pass ? f0v : f1v;  f1i = pass ? f0i : f1i;
        f0v = pass ? v   : f0v;  f0i = pass ? ci  : f0i;
        cnt += pass;
        if (__any(cnt >= 4)) {
          #pragma unroll 1
          for (int e = 3; e >= 0; --e) {   // oldest first
            float cv = (e==3) ? f3v : (e==2) ? f2v : (e==1) ? f1v : f0v;
            int  cix = (e==3) ? f3i : (e==2) ? f2i : (e==1) ? f1i : f0i;
            ins20(Lv, Li, cv, cix);
          }
          f0v = f1v = f2v = f3v = NINF;
          cnt = 0;
        }
      }
    }
  }
  { // drain FIFO
    #pragma unroll 1
    for (int e = 3; e >= 0; --e) {
      float cv = (e==3) ? f3v : (e==2) ? f2v : (e==1) ? f1v : f0v;
      int  cix = (e==3) ? f3i : (e==2) ? f2i : (e==1) ? f1i : f0i;
      ins20(Lv, Li, cv, cix);
    }
  }

  // merge the 4 per-wave partial lists per row (full (val, idx asc) comparator)
  __syncthreads();
  float* mV = smem;                 // [4][64][20] floats
  int*   mI = (int*)smem + 5120;    // [4][64][20] ints
  #pragma unroll
  for (int k = 0; k < 20; ++k) {
    mV[(w*64 + l)*20 + k] = Lv[k];
    mI[(w*64 + l)*20 + k] = Li[k];
  }
  __syncthreads();
  if (w == 0) {
    for (int ws = 1; ws < 4; ++ws) {
      #pragma unroll
      for (int k = 0; k < 20; ++k) {
        float cv = mV[(ws*64 + l)*20 + k];
        int   ci = mI[(ws*64 + l)*20 + k];
        if (better(cv, ci, Lv[19], Li[19])) {
          float c0 = cv; int i0 = ci;
          #pragma unroll
          for (int k2 = 0; k2 < 20; ++k2) {
            bool c = better(c0, i0, Lv[k2], Li[k2]);
            float nv = c ? c0 : Lv[k2];
            int   ni = c ? i0 : Li[k2];
            float ov = Lv[k2]; int oi = Li[k2];
            c0 = c ? ov : c0;
            i0 = c ? oi : i0;
            Lv[k2] = nv; Li[k2] = ni;
          }
        }
      }
    }
    int* dst = nidx + ((size_t)b*NPTS + row0 + l)*NEIGHS;
    #pragma unroll
    for (int k = 0; k < 20; ++k) dst[k] = Li[k];
  }
}

// K3: per-point neighbor max -> X -> v = Wb@X -> sc1/sc2/ret. One wave per point.
__global__ __launch_bounds__(256) void k_score(const float* __restrict__ pts,
    const float* __restrict__ G1, const float* __restrict__ G2,
    const int* __restrict__ nidx, const int* __restrict__ perm,
    const float* __restrict__ Wb,
    const float* __restrict__ b2g, const float* __restrict__ b2b,
    const float* __restrict__ b2m, const float* __restrict__ b2v,
    const float* __restrict__ bb,
    float* __restrict__ sc1w, float* __restrict__ out) {
  const int b = blockIdx.y;
  const int n0 = blockIdx.x * 16;
  const int tid = threadIdx.x, l = tid & 63, w = tid >> 6;
  __shared__ float WbS[64*65];
  for (int i = tid; i < 64*64; i += 256) WbS[(i >> 6)*65 + (i & 63)] = Wb[i];
  __syncthreads();
  const float sc2v = b2g[l] / sqrtf(b2v[l] + EPSV);
  const float mean2 = b2m[l], beta2 = b2b[l];
  const float bbv = bb[0];
  const float* G1b = G1 + (size_t)b*NPTS*NH;
  for (int it = 0; it < 4; ++it) {
    const int n = n0 + it*4 + w;
    const size_t ro = (size_t)b*NPTS*NH + (size_t)n*NH;
    const float base = G2[ro + l] - G1[ro + l];
    const int* nb = nidx + ((size_t)b*NPTS + n)*NEIGHS;
    float mx = NINF;
    #pragma unroll
    for (int k = 0; k < NEIGHS; ++k) {
      int m = nb[k];
      float val = G1b[(size_t)m*NH + l] + base;
      float y = (val - mean2) * sc2v + beta2;
      y = (y >= 0.f) ? y : 0.2f*y;
      mx = fmaxf(mx, y);
    }
    float X = 1.f / (1.f + expf(-mx));
    double v = 0.0;
    #pragma unroll
    for (int d = 0; d < 64; ++d) {
      float xd = __shfl(X, d, 64);
      v += (double)WbS[l*65 + d] * (double)xd;
    }
    float p1 = pts[ro + l];
    int pn = perm[n];
    float p2 = pts[(size_t)b*NPTS*NH + (size_t)pn*NH + l];
    double s1 = (double)p1 * v;
    double s2 = (double)p2 * v;
    #pragma unroll
    for (int off = 32; off > 0; off >>= 1) {
      s1 += __shfl_xor(s1, off, 64);
      s2 += __shfl_xor(s2, off, 64);
    }
    if (l == 0) {
      float r1 = (float)(s1 + (double)bbv);
      float r2 = (float)(s2 + (double)bbv);
      sc1w[(size_t)b*NPTS + n] = r1;
      out[OFF_RET + (size_t)b*2*NPTS + n] = r1;
      out[OFF_RET + (size_t)b*2*NPTS + NPTS + n] = r2;
    }
  }
}

// K4: per-batch exact top-512 (value desc, idx asc) via u64 bitonic sort + gathers
__global__ __launch_bounds__(256) void k_select(const float* __restrict__ sc1w,
    const float* __restrict__ seq1, const float* __restrict__ xyz,
    float* __restrict__ out) {
  const int b = blockIdx.x, tid = threadIdx.x;
  __shared__ unsigned long long keys[NPTS];
  __shared__ float valS[KSEL];
  __shared__ int idxS[KSEL];
  for (int i = tid; i < NPTS; i += 256) {
    float f = sc1w[(size_t)b*NPTS + i];
    unsigned u = __float_as_uint(f);
    u = (u & 0x80000000u) ? ~u : (u | 0x80000000u);   // ascending-order map
    keys[i] = ((unsigned long long)(~u) << 32) | (unsigned)i; // asc sort = value desc, idx asc
  }
  __syncthreads();
  for (int k = 2; k <= NPTS; k <<= 1) {
    for (int j = k >> 1; j > 0; j >>= 1) {
      for (int i = tid; i < NPTS; i += 256) {
        int l2 = i ^ j;
        if (l2 > i) {
          unsigned long long a = keys[i], c = keys[l2];
          bool up = ((i & k) == 0);
          if ((a > c) == up) { keys[i] = c; keys[l2] = a; }
        }
      }
      __syncthreads();
    }
  }
  for (int i = tid; i < KSEL; i += 256) {
    unsigned long long key = keys[i];
    int sidx = (int)(key & 0xffffffffULL);
    unsigned u = ~(unsigned)(key >> 32);
    unsigned fb = (u & 0x80000000u) ? (u & 0x7fffffffu) : ~u;
    float f = __uint_as_float(fb);
    float val = 1.f / (1.f + expf(-f));
    valS[i] = val; idxS[i] = sidx;
    out[OFF_VAL + (size_t)b*KSEL + i] = val;
    out[OFF_IDX + (size_t)b*KSEL + i] = (float)sidx;
  }
  __syncthreads();
  for (int t = tid; t < NH*KSEL; t += 256) {
    int c = t >> 9, i = t & (KSEL-1);
    float sv = seq1[((size_t)b*NH + c)*NPTS + idxS[i]];
    out[OFF_SEQ + (((size_t)b*NH + c) << 9) + i] = sv * valS[i];
  }
  for (int t = tid; t < 3*KSEL; t += 256) {
    int c = t >> 9, i = t & (KSEL-1);
    float xv = xyz[((size_t)b*3 + c)*NPTS + idxS[i]];
    out[OFF_XST + (((size_t)b*3 + c) << 9) + i] = xv;
    out[OFF_XO  + (((size_t)b*3 + c) << 9) + i] = xv * valS[i];
  }
}

extern "C" void kernel_launch(void* const* d_in, const int* in_sizes, int n_in,
                              void* d_out, int out_size, void* d_ws, size_t ws_size,
                              hipStream_t stream) {
  const float* xyz  = (const float*)d_in[0];
  const float* seq1 = (const float*)d_in[1];
  const int*   perm = (const int*)d_in[2];
  const float* Wfc  = (const float*)d_in[3];
  const float* bfc  = (const float*)d_in[4];
  const float* b1g  = (const float*)d_in[5];
  const float* b1b  = (const float*)d_in[6];
  const float* b1m  = (const float*)d_in[7];
  const float* b1v  = (const float*)d_in[8];
  const float* Wec  = (const float*)d_in[9];
  const float* b2g  = (const float*)d_in[10];
  const float* b2b  = (const float*)d_in[11];
  const float* b2m  = (const float*)d_in[12];
  const float* b2v  = (const float*)d_in[13];
  const float* Wb   = (const float*)d_in[14];
  const float* bb   = (const float*)d_in[15];
  float* out = (float*)d_out;

  float* ws   = (float*)d_ws;
  float* pts  = ws;
  float* G1   = pts + (size_t)NB*NPTS*NH;
  float* G2   = G1  + (size_t)NB*NPTS*NH;
  float* x2   = G2  + (size_t)NB*NPTS*NH;
  float* sc1w = x2  + (size_t)NB*NPTS;
  int*   nidx = (int*)(sc1w + (size_t)NB*NPTS);

  hipLaunchKernelGGL(k_fc, dim3(NPTS/64, NB), dim3(64), 0, stream,
                     seq1, Wfc, bfc, b1g, b1b, b1m, b1v, Wec, pts, G1, G2, x2);
  hipLaunchKernelGGL(k_knn, dim3(NPTS/64, NB), dim3(256), 0, stream,
                     pts, x2, nidx);
  hipLaunchKernelGGL(k_score, dim3(NPTS/16, NB), dim3(256), 0, stream,
                     pts, G1, G2, nidx, perm, Wb, b2g, b2b, b2m, b2v, bb, sc1w, out);
  hipLaunchKernelGGL(k_select, dim3(NB), dim3(256), 0, stream,
                     sc1w, seq1, xyz, out);
}